// Round 1
// baseline (59.307 us; speedup 1.0000x reference)
//
#include <hip/hip_runtime.h>

#define L_ 48
#define P_ 2048
#define D_ 50
#define AL_ 5
#define OH_ 255
#define NNODES (L_*P_)          // 98304
#define NWORDS (NNODES/32)      // 3072
#define MAXN 4096
#define NTHREADS 1024
#define NWAVES 16
#define NPT (NNODES/NTHREADS)   // 96 nodes per thread for compaction

__device__ __forceinline__ int find_slot(const int* lst, int count, int key) {
    int lo = 0, hi = count - 1;
    while (lo < hi) { int mid = (lo + hi) >> 1; if (lst[mid] < key) lo = mid + 1; else hi = mid; }
    return lo;
}

__device__ __forceinline__ float dotrow(const float* __restrict__ W, const float* in, int len) {
    float a0 = 0.f, a1 = 0.f, a2 = 0.f, a3 = 0.f;
    int j = 0;
    for (; j + 4 <= len; j += 4) {
        a0 += W[j] * in[j];
        a1 += W[j+1] * in[j+1];
        a2 += W[j+2] * in[j+2];
        a3 += W[j+3] * in[j+3];
    }
    for (; j < len; ++j) a0 += W[j] * in[j];
    return (a0 + a1) + (a2 + a3);
}

__global__ __launch_bounds__(NTHREADS)
void formula_kernel(const int* __restrict__ node_type,
                    const int* __restrict__ children,
                    const float* __restrict__ onehot,
                    const float* __restrict__ W_leaf,  const float* __restrict__ b_leaf,
                    const float* __restrict__ W_unary, const float* __restrict__ b_unary,
                    const float* __restrict__ W_exist, const float* __restrict__ b_exist,
                    const float* __restrict__ W_univ,  const float* __restrict__ b_univ,
                    const float* __restrict__ W_bin,   const float* __restrict__ b_bin,
                    const float* __restrict__ W_fun,   const float* __restrict__ b_fun,
                    const float* __restrict__ W_pred,  const float* __restrict__ b_pred,
                    const float* __restrict__ W_final, const float* __restrict__ b_final,
                    float* __restrict__ out, float* __restrict__ emb)
{
    __shared__ unsigned mask[NWORDS];      // 12 KB needed-node bitmask
    __shared__ int list[MAXN];             // sorted needed-node indices
    __shared__ int scanbuf[NTHREADS];
    __shared__ int lev_begin[L_ + 1];
    __shared__ int count_sh;
    __shared__ float leafb[NWAVES][D_];
    __shared__ float inbuf[NWAVES][6 * D_];   // up to 300 concat inputs per wave
    __shared__ int   nzj[NWAVES][16];
    __shared__ float nzv[NWAVES][16];

    const int tid  = threadIdx.x;
    const int lane = tid & 63;
    const int wave = tid >> 6;

    // ---- Phase 0: zero bitmask, seed the root node ----
    for (int i = tid; i < NWORDS; i += NTHREADS) mask[i] = 0u;
    __syncthreads();
    if (tid == 0) mask[(NNODES - 1) >> 5] = (1u << ((NNODES - 1) & 31));
    __syncthreads();

    // ---- Phase 1: mark ancestors, descending levels (children strictly lower) ----
    for (int l = L_ - 1; l >= 1; --l) {
        for (int p = tid; p < P_; p += NTHREADS) {
            int n = l * P_ + p;
            if (mask[n >> 5] & (1u << (n & 31))) {
                #pragma unroll
                for (int k = 0; k < AL_; ++k) {
                    int c = children[n * AL_ + k];
                    if (c >= 0) atomicOr(&mask[c >> 5], 1u << (c & 31));
                }
            }
        }
        __syncthreads();
    }

    // ---- Phase 2: deterministic compaction into sorted list ----
    int cnt = 0;
    const int base = tid * NPT;
    for (int i = 0; i < NPT; ++i) {
        int n = base + i;
        if (mask[n >> 5] & (1u << (n & 31))) cnt++;
    }
    scanbuf[tid] = cnt;
    __syncthreads();
    for (int off = 1; off < NTHREADS; off <<= 1) {
        int v = (tid >= off) ? scanbuf[tid - off] : 0;
        __syncthreads();
        scanbuf[tid] += v;
        __syncthreads();
    }
    int wrote = scanbuf[tid] - cnt;               // exclusive prefix
    if (tid == NTHREADS - 1) count_sh = scanbuf[tid];
    __syncthreads();
    int count = count_sh;
    if (count > MAXN) count = MAXN;               // safety; expected count ~ 26
    for (int i = 0; i < NPT; ++i) {
        int n = base + i;
        if (mask[n >> 5] & (1u << (n & 31))) {
            if (wrote < MAXN) list[wrote] = n;
            wrote++;
        }
    }
    __syncthreads();

    // ---- Phase 3: level boundaries in the sorted list ----
    if (tid <= L_) {
        int key = tid * P_;
        int lo = 0, hi = count;
        while (lo < hi) { int mid = (lo + hi) >> 1; if (list[mid] < key) lo = mid + 1; else hi = mid; }
        lev_begin[tid] = lo;
    }
    __syncthreads();

    // ---- Phase 4: compute needed nodes, ascending levels; one wave per node ----
    for (int l = 0; l < L_; ++l) {
        const int s0 = lev_begin[l], s1 = lev_begin[l + 1];
        for (int chunk = s0; chunk < s1; chunk += NWAVES) {
            const int idx = chunk + wave;
            if (idx < s1) {
                const int n  = list[idx];
                const int nt = node_type[n];
                const int ch0 = children[n * AL_ + 0];
                const int ch1 = children[n * AL_ + 1];

                const bool need_leaf = (nt == 0) || (nt >= 4);
                if (need_leaf) {
                    // onehot row is sparse (exactly 2 ones) -> gather nonzeros, wave-scan order
                    const float* oh = onehot + (size_t)n * OH_;
                    float v[4]; int c2 = 0;
                    #pragma unroll
                    for (int t = 0; t < 4; ++t) {
                        int j = lane * 4 + t;
                        v[t] = (j < OH_) ? oh[j] : 0.0f;
                        if (v[t] != 0.0f) c2++;
                    }
                    int incl = c2;
                    #pragma unroll
                    for (int d = 1; d < 64; d <<= 1) {
                        int o = __shfl_up(incl, d);
                        if (lane >= d) incl += o;
                    }
                    const int excl = incl - c2;
                    const int total = __shfl(incl, 63);
                    if (total <= 16) {
                        int pos = excl;
                        #pragma unroll
                        for (int t = 0; t < 4; ++t) {
                            if (v[t] != 0.0f) { nzj[wave][pos] = lane * 4 + t; nzv[wave][pos] = v[t]; pos++; }
                        }
                    }
                    __builtin_amdgcn_wave_barrier();
                    if (lane < D_) {
                        float s = b_leaf[lane];
                        if (total <= 16) {
                            for (int i = 0; i < total; ++i)
                                s += nzv[wave][i] * W_leaf[lane * OH_ + nzj[wave][i]];
                        } else {
                            s += dotrow(W_leaf + lane * OH_, oh, OH_);  // dense fallback
                        }
                        leafb[wave][lane] = fmaxf(s, 0.0f);
                    }
                    __builtin_amdgcn_wave_barrier();
                }

                float outv = 0.0f;
                if (nt == 0) {
                    if (lane < D_) outv = leafb[wave][lane];
                } else if (nt <= 3) {
                    if (lane < D_) {
                        float c0v = 0.0f;
                        if (ch0 >= 0) { int sl = find_slot(list, count, ch0); c0v = emb[(size_t)sl * D_ + lane]; }
                        inbuf[wave][lane] = c0v;
                    }
                    __builtin_amdgcn_wave_barrier();
                    const float* W = (nt == 1) ? W_unary : (nt == 2) ? W_exist : W_univ;
                    const float* b = (nt == 1) ? b_unary : (nt == 2) ? b_exist : b_univ;
                    if (lane < D_) {
                        float s = b[lane] + dotrow(W + lane * D_, inbuf[wave], D_);
                        outv = fmaxf(s, 0.0f);
                    }
                } else if (nt == 4) {
                    if (lane < D_) {
                        float c0v = 0.0f, c1v = 0.0f;
                        if (ch0 >= 0) { int sl = find_slot(list, count, ch0); c0v = emb[(size_t)sl * D_ + lane]; }
                        if (ch1 >= 0) { int sl = find_slot(list, count, ch1); c1v = emb[(size_t)sl * D_ + lane]; }
                        inbuf[wave][lane]          = c0v;
                        inbuf[wave][D_ + lane]     = leafb[wave][lane];
                        inbuf[wave][2 * D_ + lane] = c1v;
                    }
                    __builtin_amdgcn_wave_barrier();
                    if (lane < D_) {
                        float s = b_bin[lane] + dotrow(W_bin + lane * 3 * D_, inbuf[wave], 3 * D_);
                        outv = fmaxf(s, 0.0f);
                    }
                } else {
                    // fun (5) / pred (6): fin = [leaf | ce0..ce4]
                    if (lane < D_) inbuf[wave][lane] = leafb[wave][lane];
                    #pragma unroll
                    for (int k = 0; k < AL_; ++k) {
                        int c = children[n * AL_ + k];
                        if (lane < D_) {
                            float cv = 0.0f;
                            if (c >= 0) { int sl = find_slot(list, count, c); cv = emb[(size_t)sl * D_ + lane]; }
                            inbuf[wave][D_ + k * D_ + lane] = cv;
                        }
                    }
                    __builtin_amdgcn_wave_barrier();
                    const float* W = (nt == 5) ? W_fun : W_pred;
                    const float* b = (nt == 5) ? b_fun : b_pred;
                    if (lane < D_) {
                        float s = b[lane] + dotrow(W + lane * 6 * D_, inbuf[wave], 6 * D_);
                        outv = fmaxf(s, 0.0f);
                    }
                }
                if (lane < D_) emb[(size_t)idx * D_ + lane] = outv;
            }
        }
        __syncthreads();   // level barrier: next level may read any lower-level emb
    }

    // ---- Phase 5: final projection from the root (largest node index = last slot) ----
    if (tid < D_) inbuf[0][tid] = emb[(size_t)(count - 1) * D_ + tid];
    __syncthreads();
    for (int o = tid; o < OH_; o += NTHREADS) {
        float s = b_final[o] + dotrow(W_final + o * D_, inbuf[0], D_);
        out[o] = s;
    }
}

extern "C" void kernel_launch(void* const* d_in, const int* in_sizes, int n_in,
                              void* d_out, int out_size, void* d_ws, size_t ws_size,
                              hipStream_t stream) {
    const int*   node_type = (const int*)d_in[0];
    const int*   children  = (const int*)d_in[1];
    const float* onehot    = (const float*)d_in[2];
    const float* W_leaf  = (const float*)d_in[3];  const float* b_leaf  = (const float*)d_in[4];
    const float* W_unary = (const float*)d_in[5];  const float* b_unary = (const float*)d_in[6];
    const float* W_exist = (const float*)d_in[7];  const float* b_exist = (const float*)d_in[8];
    const float* W_univ  = (const float*)d_in[9];  const float* b_univ  = (const float*)d_in[10];
    const float* W_bin   = (const float*)d_in[11]; const float* b_bin   = (const float*)d_in[12];
    const float* W_fun   = (const float*)d_in[13]; const float* b_fun   = (const float*)d_in[14];
    const float* W_pred  = (const float*)d_in[15]; const float* b_pred  = (const float*)d_in[16];
    const float* W_final = (const float*)d_in[17]; const float* b_final = (const float*)d_in[18];

    float* out = (float*)d_out;
    float* emb = (float*)d_ws;   // MAXN * D_ * 4 = 800 KB compact embedding store

    formula_kernel<<<1, NTHREADS, 0, stream>>>(
        node_type, children, onehot,
        W_leaf, b_leaf, W_unary, b_unary, W_exist, b_exist, W_univ, b_univ,
        W_bin, b_bin, W_fun, b_fun, W_pred, b_pred, W_final, b_final,
        out, emb);
}

// Round 2
// 33.906 us; speedup vs baseline: 1.7491x; 1.7491x over previous
//
#include <hip/hip_runtime.h>

#define L_ 48
#define P_ 2048
#define D_ 50
#define AL_ 5
#define OH_ 255
#define NNODES (L_*P_)          // 98304
#define MAXN_ 448               // expected live-set ~26; huge safety margin
#define HSZ 1024                // hash slots (power of 2)
#define NTHREADS 512
#define NWAVES 8

__device__ __forceinline__ float dotrow(const float* __restrict__ W, const float* in, int len) {
    float a0 = 0.f, a1 = 0.f, a2 = 0.f, a3 = 0.f;
    int j = 0;
    for (; j + 4 <= len; j += 4) {
        a0 += W[j] * in[j];
        a1 += W[j+1] * in[j+1];
        a2 += W[j+2] * in[j+2];
        a3 += W[j+3] * in[j+3];
    }
    for (; j < len; ++j) a0 += W[j] * in[j];
    return (a0 + a1) + (a2 + a3);
}

// touch an array to warm L2; returns a live-kept dummy sum
__device__ __forceinline__ float pf(const float* __restrict__ p, int n, int t, int nth) {
    float s = 0.f;
    for (int i = t * 2; i + 1 < n; i += nth * 2) {
        float2 v = *reinterpret_cast<const float2*>(p + i);
        s += v.x + v.y;
    }
    return s;
}

__global__ __launch_bounds__(NTHREADS)
void formula_kernel(const int* __restrict__ node_type,
                    const int* __restrict__ children,
                    const float* __restrict__ onehot,
                    const float* __restrict__ W_leaf,  const float* __restrict__ b_leaf,
                    const float* __restrict__ W_unary, const float* __restrict__ b_unary,
                    const float* __restrict__ W_exist, const float* __restrict__ b_exist,
                    const float* __restrict__ W_univ,  const float* __restrict__ b_univ,
                    const float* __restrict__ W_bin,   const float* __restrict__ b_bin,
                    const float* __restrict__ W_fun,   const float* __restrict__ b_fun,
                    const float* __restrict__ W_pred,  const float* __restrict__ b_pred,
                    const float* __restrict__ W_final, const float* __restrict__ b_final,
                    float* __restrict__ out)
{
    __shared__ int h_key[HSZ];
    __shared__ int h_val[HSZ];
    __shared__ int list[MAXN_];
    __shared__ int nt_l[MAXN_];
    __shared__ int dep[MAXN_];
    __shared__ int order[MAXN_];
    __shared__ int ch_l[MAXN_][AL_];
    __shared__ int dcnt[48], doff[48], dfill[48];
    __shared__ int cnt_sh, maxd_sh;
    __shared__ float emb_s[MAXN_][D_];           // ~90 KB
    __shared__ float inbuf[NWAVES][6 * D_];
    __shared__ int   nzj[NWAVES][16];
    __shared__ float nzv[NWAVES][16];

    const int tid  = threadIdx.x;
    const int lane = tid & 63;
    const int wave = tid >> 6;
    volatile int* vcnt = &cnt_sh;

    if (wave == 0) {
        // ================= wave 0: discovery / scheduling =================
        for (int i = lane; i < HSZ; i += 64) h_key[i] = -1;
        __builtin_amdgcn_wave_barrier();
        if (lane == 0) {
            cnt_sh = 1;
            list[0] = NNODES - 1;                 // root is slot 0
            unsigned h = ((unsigned)(NNODES - 1) * 2654435761u) >> 16;
            for (;;) { int i = (int)(h & (HSZ - 1));
                       if (h_key[i] == -1) { h_key[i] = NNODES - 1; h_val[i] = 0; break; } ++h; }
        }
        __builtin_amdgcn_wave_barrier();

        // BFS frontier expansion (rounds = dependency depth, ~8)
        int fs = 0, fe = 1;
        for (int round = 0; round < 48 && fs < fe; ++round) {
            const int npairs = (fe - fs) * AL_;
            for (int t = lane; t < npairs; t += 64) {
                int n = list[fs + t / AL_];
                int c = children[(size_t)n * AL_ + (t % AL_)];
                if (c >= 0) {
                    unsigned h = ((unsigned)c * 2654435761u) >> 16;
                    for (;;) {
                        int i = (int)(h & (HSZ - 1));
                        int prev = atomicCAS(&h_key[i], -1, c);
                        if (prev == -1) {
                            int pos = atomicAdd(&cnt_sh, 1);
                            h_val[i] = pos;
                            if (pos < MAXN_) list[pos] = c;
                            break;
                        }
                        if (prev == c) break;
                        ++h;
                    }
                }
            }
            __builtin_amdgcn_wave_barrier();
            fs = fe;
            int c2 = *vcnt;
            fe = c2 < MAXN_ ? c2 : MAXN_;
            __builtin_amdgcn_wave_barrier();
        }

        const int count = (*vcnt < MAXN_) ? *vcnt : MAXN_;

        // resolve node types + child slot ids
        for (int t = lane; t < count * 6; t += 64) {
            int i = t / 6, j = t % 6;
            int n = list[i];
            if (j == 0) {
                nt_l[i] = node_type[n];
            } else {
                int c = children[(size_t)n * AL_ + (j - 1)];
                int sl = -1;
                if (c >= 0) {
                    unsigned h = ((unsigned)c * 2654435761u) >> 16;
                    for (;;) {
                        int ii = (int)(h & (HSZ - 1));
                        if (h_key[ii] == c) { sl = h_val[ii]; break; }
                        ++h;
                    }
                    if (sl >= MAXN_) sl = -1;     // safety
                }
                ch_l[i][j - 1] = sl;
            }
        }
        __builtin_amdgcn_wave_barrier();

        // depth fixpoint (monotone, converges in ~max-depth iters; all LDS)
        volatile int* vdep = dep;
        for (int i = lane; i < count; i += 64) vdep[i] = 0;
        __builtin_amdgcn_wave_barrier();
        for (int it = 0; it < 48; ++it) {
            bool anych = false;
            for (int i = lane; i < count; i += 64) {
                int d = 0;
                #pragma unroll
                for (int k = 0; k < AL_; ++k) {
                    int cs = ch_l[i][k];
                    if (cs >= 0) { int dd = vdep[cs] + 1; if (dd > d) d = dd; }
                }
                if (d > vdep[i]) { vdep[i] = d; anych = true; }
            }
            __builtin_amdgcn_wave_barrier();
            if (!__any(anych)) break;
        }

        // counting sort by depth
        for (int i = lane; i < 48; i += 64) { dcnt[i] = 0; dfill[i] = 0; }
        __builtin_amdgcn_wave_barrier();
        for (int i = lane; i < count; i += 64) atomicAdd(&dcnt[dep[i]], 1);
        __builtin_amdgcn_wave_barrier();
        {
            int v = (lane < 48) ? dcnt[lane] : 0;
            int incl = v;
            #pragma unroll
            for (int dlt = 1; dlt < 64; dlt <<= 1) {
                int o = __shfl_up(incl, dlt);
                if (lane >= dlt) incl += o;
            }
            if (lane < 48) doff[lane] = incl - v;
            unsigned long long b = __ballot(lane < 48 && v != 0);
            if (lane == 0) maxd_sh = 63 - __builtin_clzll(b);
        }
        __builtin_amdgcn_wave_barrier();
        for (int i = lane; i < count; i += 64) {
            int d = dep[i];
            int pos = doff[d] + atomicAdd(&dfill[d], 1);
            order[pos] = i;
        }
    } else {
        // ================= waves 1..7: warm L2 with all weights =================
        const int t = tid - 64, nth = NTHREADS - 64;
        float s = 0.f;
        s += pf(W_leaf,  D_ * OH_,    t, nth);
        s += pf(W_unary, D_ * D_,     t, nth);
        s += pf(W_exist, D_ * D_,     t, nth);
        s += pf(W_univ,  D_ * D_,     t, nth);
        s += pf(W_bin,   D_ * 3 * D_, t, nth);
        s += pf(W_fun,   D_ * 6 * D_, t, nth);
        s += pf(W_pred,  D_ * 6 * D_, t, nth);
        s += pf(W_final, OH_ * D_,    t, nth);
        s += pf(b_leaf, D_, t, nth);  s += pf(b_unary, D_, t, nth);
        s += pf(b_exist, D_, t, nth); s += pf(b_univ, D_, t, nth);
        s += pf(b_bin, D_, t, nth);   s += pf(b_fun, D_, t, nth);
        s += pf(b_pred, D_, t, nth);  s += pf(b_final, OH_, t, nth);
        asm volatile("" :: "v"(s));
    }
    __syncthreads();

    const int count = (cnt_sh < MAXN_) ? cnt_sh : MAXN_;
    const int maxd  = maxd_sh;

    // warm L1/L2 with the onehot rows of the live set (coalesced, once)
    {
        float s2 = 0.f;
        for (int t = tid; t < count * 256; t += NTHREADS) {
            int i = t >> 8, j = t & 255;
            if (j < OH_) s2 += onehot[(size_t)list[i] * OH_ + j];
        }
        asm volatile("" :: "v"(s2));
    }

    // ================= compute by dependency depth, one wave per node =================
    for (int d = 0; d <= maxd; ++d) {
        const int s0 = doff[d], cn = dcnt[d];
        for (int jj = wave; jj < cn; jj += NWAVES) {
            const int slot = order[s0 + jj];
            const int n  = list[slot];
            const int nt = nt_l[slot];

            float leafv = 0.0f;
            const bool need_leaf = (nt == 0) || (nt >= 4);
            if (need_leaf) {
                const float* oh = onehot + (size_t)n * OH_;
                float v[4]; int c2 = 0;
                #pragma unroll
                for (int t = 0; t < 4; ++t) {
                    int j = lane * 4 + t;
                    v[t] = (j < OH_) ? oh[j] : 0.0f;
                    if (v[t] != 0.0f) c2++;
                }
                int incl = c2;
                #pragma unroll
                for (int dlt = 1; dlt < 64; dlt <<= 1) {
                    int o = __shfl_up(incl, dlt);
                    if (lane >= dlt) incl += o;
                }
                const int excl = incl - c2;
                const int total = __shfl(incl, 63);
                if (total <= 16) {
                    int pos = excl;
                    #pragma unroll
                    for (int t = 0; t < 4; ++t)
                        if (v[t] != 0.0f) { nzj[wave][pos] = lane * 4 + t; nzv[wave][pos] = v[t]; pos++; }
                }
                __builtin_amdgcn_wave_barrier();
                if (lane < D_) {
                    float sacc = b_leaf[lane];
                    if (total <= 16) {
                        for (int i2 = 0; i2 < total; ++i2)
                            sacc += nzv[wave][i2] * W_leaf[lane * OH_ + nzj[wave][i2]];
                    } else {
                        sacc += dotrow(W_leaf + lane * OH_, oh, OH_);
                    }
                    leafv = fmaxf(sacc, 0.0f);
                }
                __builtin_amdgcn_wave_barrier();
            }

            float outv = 0.0f;
            if (nt == 0) {
                outv = leafv;
            } else if (nt <= 3) {
                const int cs0 = ch_l[slot][0];
                if (lane < D_) inbuf[wave][lane] = (cs0 >= 0) ? emb_s[cs0][lane] : 0.0f;
                __builtin_amdgcn_wave_barrier();
                const float* W = (nt == 1) ? W_unary : (nt == 2) ? W_exist : W_univ;
                const float* b = (nt == 1) ? b_unary : (nt == 2) ? b_exist : b_univ;
                if (lane < D_)
                    outv = fmaxf(b[lane] + dotrow(W + lane * D_, inbuf[wave], D_), 0.0f);
            } else if (nt == 4) {
                const int cs0 = ch_l[slot][0], cs1 = ch_l[slot][1];
                if (lane < D_) {
                    inbuf[wave][lane]          = (cs0 >= 0) ? emb_s[cs0][lane] : 0.0f;
                    inbuf[wave][D_ + lane]     = leafv;
                    inbuf[wave][2 * D_ + lane] = (cs1 >= 0) ? emb_s[cs1][lane] : 0.0f;
                }
                __builtin_amdgcn_wave_barrier();
                if (lane < D_)
                    outv = fmaxf(b_bin[lane] + dotrow(W_bin + lane * 3 * D_, inbuf[wave], 3 * D_), 0.0f);
            } else {
                if (lane < D_) {
                    inbuf[wave][lane] = leafv;
                    #pragma unroll
                    for (int k = 0; k < AL_; ++k) {
                        int cs = ch_l[slot][k];
                        inbuf[wave][D_ + k * D_ + lane] = (cs >= 0) ? emb_s[cs][lane] : 0.0f;
                    }
                }
                __builtin_amdgcn_wave_barrier();
                const float* W = (nt == 5) ? W_fun : W_pred;
                const float* b = (nt == 5) ? b_fun : b_pred;
                if (lane < D_)
                    outv = fmaxf(b[lane] + dotrow(W + lane * 6 * D_, inbuf[wave], 6 * D_), 0.0f);
            }
            if (lane < D_) emb_s[slot][lane] = outv;
        }
        __syncthreads();
    }

    // ================= final projection from root (slot 0) =================
    for (int o = tid; o < OH_; o += NTHREADS) {
        float s = b_final[o];
        const float* W = W_final + o * D_;
        #pragma unroll
        for (int j = 0; j < D_; ++j) s += W[j] * emb_s[0][j];
        out[o] = s;
    }
}

extern "C" void kernel_launch(void* const* d_in, const int* in_sizes, int n_in,
                              void* d_out, int out_size, void* d_ws, size_t ws_size,
                              hipStream_t stream) {
    const int*   node_type = (const int*)d_in[0];
    const int*   children  = (const int*)d_in[1];
    const float* onehot    = (const float*)d_in[2];
    const float* W_leaf  = (const float*)d_in[3];  const float* b_leaf  = (const float*)d_in[4];
    const float* W_unary = (const float*)d_in[5];  const float* b_unary = (const float*)d_in[6];
    const float* W_exist = (const float*)d_in[7];  const float* b_exist = (const float*)d_in[8];
    const float* W_univ  = (const float*)d_in[9];  const float* b_univ  = (const float*)d_in[10];
    const float* W_bin   = (const float*)d_in[11]; const float* b_bin   = (const float*)d_in[12];
    const float* W_fun   = (const float*)d_in[13]; const float* b_fun   = (const float*)d_in[14];
    const float* W_pred  = (const float*)d_in[15]; const float* b_pred  = (const float*)d_in[16];
    const float* W_final = (const float*)d_in[17]; const float* b_final = (const float*)d_in[18];

    float* out = (float*)d_out;

    formula_kernel<<<1, NTHREADS, 0, stream>>>(
        node_type, children, onehot,
        W_leaf, b_leaf, W_unary, b_unary, W_exist, b_exist, W_univ, b_univ,
        W_bin, b_bin, W_fun, b_fun, W_pred, b_pred, W_final, b_final,
        out);
}

// Round 3
// 23.404 us; speedup vs baseline: 2.5341x; 1.4487x over previous
//
#include <hip/hip_runtime.h>

#define L_ 48
#define P_ 2048
#define D_ 50
#define AL_ 5
#define OH_ 255
#define NNODES (L_*P_)          // 98304
#define MAXN_ 256               // expected live-set ~26
#define HSZ 1024                // hash slots (power of 2)
#define NTHREADS 512
#define NWAVES 8

// dot of a 50-float W segment (global, 8B-aligned) with a 50-float LDS row
__device__ __forceinline__ float dot50(const float* __restrict__ W, const float* in) {
    float a0 = 0.f, a1 = 0.f, a2 = 0.f, a3 = 0.f;
    #pragma unroll
    for (int j = 0; j < 48; j += 4) {
        float2 w0 = *reinterpret_cast<const float2*>(W + j);
        float2 w1 = *reinterpret_cast<const float2*>(W + j + 2);
        a0 += w0.x * in[j];
        a1 += w0.y * in[j + 1];
        a2 += w1.x * in[j + 2];
        a3 += w1.y * in[j + 3];
    }
    float2 wl = *reinterpret_cast<const float2*>(W + 48);
    a0 += wl.x * in[48];
    a1 += wl.y * in[49];
    return (a0 + a1) + (a2 + a3);
}

__device__ __forceinline__ float dotrow(const float* __restrict__ W, const float* in, int len) {
    float a0 = 0.f, a1 = 0.f, a2 = 0.f, a3 = 0.f;
    int j = 0;
    for (; j + 4 <= len; j += 4) {
        a0 += W[j] * in[j]; a1 += W[j+1] * in[j+1];
        a2 += W[j+2] * in[j+2]; a3 += W[j+3] * in[j+3];
    }
    for (; j < len; ++j) a0 += W[j] * in[j];
    return (a0 + a1) + (a2 + a3);
}

__device__ __forceinline__ float pf4(const float* __restrict__ p, int n, int t, int nth) {
    float s = 0.f;
    for (int i = t * 4; i + 3 < n; i += nth * 4) {
        float4 v = *reinterpret_cast<const float4*>(p + i);
        s += v.x + v.y + v.z + v.w;
    }
    return s;
}

__global__ __launch_bounds__(NTHREADS)
void formula_kernel(const int* __restrict__ node_type,
                    const int* __restrict__ children,
                    const float* __restrict__ onehot,
                    const float* __restrict__ W_leaf,  const float* __restrict__ b_leaf,
                    const float* __restrict__ W_unary, const float* __restrict__ b_unary,
                    const float* __restrict__ W_exist, const float* __restrict__ b_exist,
                    const float* __restrict__ W_univ,  const float* __restrict__ b_univ,
                    const float* __restrict__ W_bin,   const float* __restrict__ b_bin,
                    const float* __restrict__ W_fun,   const float* __restrict__ b_fun,
                    const float* __restrict__ W_pred,  const float* __restrict__ b_pred,
                    const float* __restrict__ W_final, const float* __restrict__ b_final,
                    float* __restrict__ out)
{
    __shared__ int h_key[HSZ];
    __shared__ int h_val[HSZ];
    __shared__ int list[MAXN_];
    __shared__ int nt_l[MAXN_];
    __shared__ int dep[MAXN_];
    __shared__ int order[MAXN_];
    __shared__ int ch_l[MAXN_][AL_];
    __shared__ int dcnt[48], doff[48], dfill[48];
    __shared__ int cnt_sh, maxd_sh;
    __shared__ float emb_s[MAXN_][D_];           // 51.2 KB
    __shared__ float leaf_s[MAXN_][D_];          // 51.2 KB
    __shared__ int   nzj[NWAVES][16];
    __shared__ float nzv[NWAVES][16];

    const int tid  = threadIdx.x;
    const int lane = tid & 63;
    const int wave = tid >> 6;
    volatile int* vcnt = &cnt_sh;

    if (wave == 0) {
        // ================= wave 0: discovery =================
        for (int i = lane; i < HSZ; i += 64) h_key[i] = -1;
        __builtin_amdgcn_wave_barrier();
        if (lane == 0) {
            cnt_sh = 1;
            list[0] = NNODES - 1;                 // root is slot 0
            unsigned h = ((unsigned)(NNODES - 1) * 2654435761u) >> 16;
            for (;;) { int i = (int)(h & (HSZ - 1));
                       if (h_key[i] == -1) { h_key[i] = NNODES - 1; h_val[i] = 0; break; } ++h; }
        }
        __builtin_amdgcn_wave_barrier();

        int fs = 0, fe = 1;
        for (int round = 0; round < 48 && fs < fe; ++round) {
            const int npairs = (fe - fs) * AL_;
            for (int base = 0; base < npairs; base += 256) {
                const int m = (npairs - base < 256) ? (npairs - base) : 256;
                int cv[4];
                #pragma unroll
                for (int u = 0; u < 4; ++u) {          // preload: one latency for all
                    int t = base + lane + u * 64;
                    cv[u] = (t < base + m)
                        ? children[(size_t)list[fs + t / AL_] * AL_ + (t % AL_)] : -1;
                }
                #pragma unroll
                for (int u = 0; u < 4; ++u) {
                    int c = cv[u];
                    if (c >= 0) {
                        unsigned h = ((unsigned)c * 2654435761u) >> 16;
                        for (;;) {
                            int i = (int)(h & (HSZ - 1));
                            int prev = atomicCAS(&h_key[i], -1, c);
                            if (prev == -1) {
                                int pos = atomicAdd(&cnt_sh, 1);
                                h_val[i] = pos;
                                if (pos < MAXN_) list[pos] = c;
                                break;
                            }
                            if (prev == c) break;
                            ++h;
                        }
                    }
                }
            }
            __builtin_amdgcn_wave_barrier();
            fs = fe;
            int c2 = *vcnt;
            fe = c2 < MAXN_ ? c2 : MAXN_;
            __builtin_amdgcn_wave_barrier();
        }

        const int count = (*vcnt < MAXN_) ? *vcnt : MAXN_;

        // resolve node types + child slot ids
        for (int t = lane; t < count * 6; t += 64) {
            int i = t / 6, j = t % 6;
            int n = list[i];
            if (j == 0) {
                nt_l[i] = node_type[n];
            } else {
                int c = children[(size_t)n * AL_ + (j - 1)];
                int sl = -1;
                if (c >= 0) {
                    unsigned h = ((unsigned)c * 2654435761u) >> 16;
                    for (;;) {
                        int ii = (int)(h & (HSZ - 1));
                        if (h_key[ii] == c) { sl = h_val[ii]; break; }
                        ++h;
                    }
                    if (sl >= MAXN_) sl = -1;
                }
                ch_l[i][j - 1] = sl;
            }
        }
    } else {
        // ================= waves 1..7: warm L2 with all weights =================
        const int t = tid - 64, nth = NTHREADS - 64;
        float s = 0.f;
        s += pf4(W_leaf,  D_ * OH_,    t, nth);
        s += pf4(W_unary, D_ * D_,     t, nth);
        s += pf4(W_exist, D_ * D_,     t, nth);
        s += pf4(W_univ,  D_ * D_,     t, nth);
        s += pf4(W_bin,   D_ * 3 * D_, t, nth);
        s += pf4(W_fun,   D_ * 6 * D_, t, nth);
        s += pf4(W_pred,  D_ * 6 * D_, t, nth);
        s += pf4(W_final, OH_ * D_,    t, nth);
        if (t < 64) {
            s += b_leaf[t % D_] + b_unary[t % D_] + b_exist[t % D_] + b_univ[t % D_]
               + b_bin[t % D_] + b_fun[t % D_] + b_pred[t % D_] + b_final[t];
        }
        asm volatile("" :: "v"(s));
    }
    __syncthreads();

    const int count = (cnt_sh < MAXN_) ? cnt_sh : MAXN_;

    if (wave == 0) {
        // ======== wave 0: depth fixpoint + counting sort (alone) ========
        volatile int* vdep = dep;
        for (int i = lane; i < count; i += 64) vdep[i] = 0;
        __builtin_amdgcn_wave_barrier();
        for (int it = 0; it < 48; ++it) {
            bool anych = false;
            for (int i = lane; i < count; i += 64) {
                int d = 0;
                #pragma unroll
                for (int k = 0; k < AL_; ++k) {
                    int cs = ch_l[i][k];
                    if (cs >= 0) { int dd = vdep[cs] + 1; if (dd > d) d = dd; }
                }
                if (d > vdep[i]) { vdep[i] = d; anych = true; }
            }
            __builtin_amdgcn_wave_barrier();
            if (!__any(anych)) break;
        }
        for (int i = lane; i < 48; i += 64) { dcnt[i] = 0; dfill[i] = 0; }
        __builtin_amdgcn_wave_barrier();
        for (int i = lane; i < count; i += 64) atomicAdd(&dcnt[dep[i]], 1);
        __builtin_amdgcn_wave_barrier();
        {
            int v = (lane < 48) ? dcnt[lane] : 0;
            int incl = v;
            #pragma unroll
            for (int dlt = 1; dlt < 64; dlt <<= 1) {
                int o = __shfl_up(incl, dlt);
                if (lane >= dlt) incl += o;
            }
            if (lane < 48) doff[lane] = incl - v;
            unsigned long long b = __ballot(lane < 48 && v != 0);
            if (lane == 0) maxd_sh = 63 - __builtin_clzll(b);
        }
        __builtin_amdgcn_wave_barrier();
        for (int i = lane; i < count; i += 64) {
            int d = dep[i];
            int pos = doff[d] + atomicAdd(&dfill[d], 1);
            order[pos] = i;
        }
    } else {
        // ======== waves 1..7: all leaf vectors in parallel ========
        for (int slot = wave - 1; slot < count; slot += NWAVES - 1) {
            const int nt = nt_l[slot];
            if (nt >= 1 && nt <= 3) continue;
            const int n = list[slot];
            const float* oh = onehot + (size_t)n * OH_;
            float v[4]; int c2 = 0;
            #pragma unroll
            for (int t = 0; t < 4; ++t) {
                int j = lane * 4 + t;
                v[t] = (j < OH_) ? oh[j] : 0.0f;
                if (v[t] != 0.0f) c2++;
            }
            int incl = c2;
            #pragma unroll
            for (int dlt = 1; dlt < 64; dlt <<= 1) {
                int o = __shfl_up(incl, dlt);
                if (lane >= dlt) incl += o;
            }
            const int excl = incl - c2;
            const int total = __shfl(incl, 63);
            if (total <= 16) {
                int pos = excl;
                #pragma unroll
                for (int t = 0; t < 4; ++t)
                    if (v[t] != 0.0f) { nzj[wave][pos] = lane * 4 + t; nzv[wave][pos] = v[t]; pos++; }
            }
            __builtin_amdgcn_wave_barrier();
            if (lane < D_) {
                float sacc = b_leaf[lane];
                if (total <= 16) {
                    for (int i2 = 0; i2 < total; ++i2)
                        sacc += nzv[wave][i2] * W_leaf[lane * OH_ + nzj[wave][i2]];
                } else {
                    sacc += dotrow(W_leaf + lane * OH_, oh, OH_);
                }
                float lv = fmaxf(sacc, 0.0f);
                if (nt == 0) emb_s[slot][lane] = lv;    // leaves are final outputs
                else         leaf_s[slot][lane] = lv;
            }
            __builtin_amdgcn_wave_barrier();
        }
    }
    __syncthreads();

    const int maxd = maxd_sh;

    // ================= compute by dependency depth, one wave per node =================
    for (int d = 1; d <= maxd; ++d) {
        const int s0 = doff[d], cn = dcnt[d];
        for (int jj = wave; jj < cn; jj += NWAVES) {
            const int slot = order[s0 + jj];
            const int nt = nt_l[slot];
            if (lane < D_) {
                float s;
                if (nt <= 3) {
                    const float* W = (nt == 1) ? W_unary : (nt == 2) ? W_exist : W_univ;
                    const float* b = (nt == 1) ? b_unary : (nt == 2) ? b_exist : b_univ;
                    s = b[lane];
                    const int cs0 = ch_l[slot][0];
                    if (cs0 >= 0) s += dot50(W + lane * D_, emb_s[cs0]);
                } else if (nt == 4) {
                    const float* W = W_bin + lane * 3 * D_;
                    s = b_bin[lane];
                    const int cs0 = ch_l[slot][0], cs1 = ch_l[slot][1];
                    if (cs0 >= 0) s += dot50(W, emb_s[cs0]);
                    s += dot50(W + D_, leaf_s[slot]);
                    if (cs1 >= 0) s += dot50(W + 2 * D_, emb_s[cs1]);
                } else {
                    const float* W = ((nt == 5) ? W_fun : W_pred) + lane * 6 * D_;
                    s = ((nt == 5) ? b_fun : b_pred)[lane] + dot50(W, leaf_s[slot]);
                    #pragma unroll
                    for (int k = 0; k < AL_; ++k) {
                        int cs = ch_l[slot][k];
                        if (cs >= 0) s += dot50(W + (1 + k) * D_, emb_s[cs]);
                    }
                }
                emb_s[slot][lane] = fmaxf(s, 0.0f);
            }
        }
        __syncthreads();
    }

    // ================= final projection from root (slot 0) =================
    for (int o = tid; o < OH_; o += NTHREADS)
        out[o] = b_final[o] + dot50(W_final + o * D_, emb_s[0]);
}

extern "C" void kernel_launch(void* const* d_in, const int* in_sizes, int n_in,
                              void* d_out, int out_size, void* d_ws, size_t ws_size,
                              hipStream_t stream) {
    const int*   node_type = (const int*)d_in[0];
    const int*   children  = (const int*)d_in[1];
    const float* onehot    = (const float*)d_in[2];
    const float* W_leaf  = (const float*)d_in[3];  const float* b_leaf  = (const float*)d_in[4];
    const float* W_unary = (const float*)d_in[5];  const float* b_unary = (const float*)d_in[6];
    const float* W_exist = (const float*)d_in[7];  const float* b_exist = (const float*)d_in[8];
    const float* W_univ  = (const float*)d_in[9];  const float* b_univ  = (const float*)d_in[10];
    const float* W_bin   = (const float*)d_in[11]; const float* b_bin   = (const float*)d_in[12];
    const float* W_fun   = (const float*)d_in[13]; const float* b_fun   = (const float*)d_in[14];
    const float* W_pred  = (const float*)d_in[15]; const float* b_pred  = (const float*)d_in[16];
    const float* W_final = (const float*)d_in[17]; const float* b_final = (const float*)d_in[18];

    float* out = (float*)d_out;

    formula_kernel<<<1, NTHREADS, 0, stream>>>(
        node_type, children, onehot,
        W_leaf, b_leaf, W_unary, b_unary, W_exist, b_exist, W_univ, b_univ,
        W_bin, b_bin, W_fun, b_fun, W_pred, b_pred, W_final, b_final,
        out);
}